// Round 19
// baseline (162.017 us; speedup 1.0000x reference)
//
#include <hip/hip_runtime.h>

// ---------------- problem constants ----------------
#define EMBED 1024
#define HEADS 16
#define HDIM  64
#define BATCH 2
#define SEQ   2048
#define MTOT  (BATCH*SEQ)          // 4096 rows in all GEMMs
#define LOG2E 1.4426950408889634f
#define QSCALE (0.125f * LOG2E)    // head_dim^-0.5 * log2(e), folded into q

typedef __attribute__((ext_vector_type(8)))  short short8;   // 8 bf16 (4 VGPR)
typedef __attribute__((ext_vector_type(4)))  float f32x4;
typedef __attribute__((ext_vector_type(16))) float f32x16;

#define MFMA(a,b,c)   __builtin_amdgcn_mfma_f32_16x16x32_bf16(a,b,c,0,0,0)
#define MFMA32(a,b,c) __builtin_amdgcn_mfma_f32_32x32x16_bf16(a,b,c,0,0,0)

__device__ __forceinline__ ushort f2bf(float f) {
  union { float f; unsigned u; } v; v.f = f;
  unsigned u = v.u;
  unsigned r = u + 0x7fffu + ((u >> 16) & 1u);   // round-to-nearest-even
  return (ushort)(r >> 16);
}
__device__ __forceinline__ unsigned packbf(float a, float b) {
  return (unsigned)f2bf(a) | ((unsigned)f2bf(b) << 16);
}
// hw packed f32x2 -> bf16x2 (single instruction)
__device__ __forceinline__ unsigned cvtpk(float lo, float hi) {
  unsigned r;
  asm("v_cvt_pk_bf16_f32 %0, %1, %2" : "=v"(r) : "v"(lo), "v"(hi));
  return r;
}
__device__ __forceinline__ uint2 cvt4(float4 v) {
  uint2 r;
  asm("v_cvt_pk_bf16_f32 %0, %2, %3\n\t"
      "v_cvt_pk_bf16_f32 %1, %4, %5"
      : "=&v"(r.x), "=&v"(r.y)
      : "v"(v.x), "v"(v.y), "v"(v.z), "v"(v.w));
  return r;
}
// async global->LDS, 16 B per lane (wave-uniform LDS base + lane*16)
__device__ __forceinline__ void gl_lds16(const ushort* g, ushort* l) {
  __builtin_amdgcn_global_load_lds(
      (const __attribute__((address_space(1))) unsigned*)g,
      (__attribute__((address_space(3))) unsigned*)l, 16, 0, 0);
}

// ================= fp32 -> bf16 convert (inputs + weights, once) =================
__global__ __launch_bounds__(256) void tobf16(
    const float* __restrict__ s0, const float* __restrict__ s1, const float* __restrict__ s2,
    const float* __restrict__ s3, const float* __restrict__ s4, const float* __restrict__ s5,
    const float* __restrict__ s6,
    ushort* __restrict__ d0, ushort* __restrict__ d1, ushort* __restrict__ d2,
    ushort* __restrict__ d3, ushort* __restrict__ d4, ushort* __restrict__ d5,
    ushort* __restrict__ d6)
{
  const int z = blockIdx.z;
  const float* s; ushort* d;
  switch (z) {
    case 0: s = s0; d = d0; break;
    case 1: s = s1; d = d1; break;
    case 2: s = s2; d = d2; break;
    case 3: s = s3; d = d3; break;
    case 4: s = s4; d = d4; break;
    case 5: s = s5; d = d5; break;
    default: s = s6; d = d6; break;
  }
  const int nch = (z < 3) ? (MTOT * EMBED / 8) : (EMBED * EMBED / 8);
  int i = blockIdx.x * 256 + threadIdx.x;
  if (i >= nch) return;
  float4 a = reinterpret_cast<const float4*>(s)[2 * i];
  float4 b = reinterpret_cast<const float4*>(s)[2 * i + 1];
  uint2 lo = cvt4(a), hi = cvt4(b);
  reinterpret_cast<uint4*>(d)[i] = make_uint4(lo.x, lo.y, hi.x, hi.y);
}

// ================= mask bit-pack =================
__global__ __launch_bounds__(256) void maskpack(const int* __restrict__ mask,
                                                unsigned long long* __restrict__ bits) {
  size_t idx = (size_t)blockIdx.x * 256 + threadIdx.x;
  unsigned long long bal = __ballot(mask[idx] != 0);
  if ((threadIdx.x & 63) == 0) bits[idx >> 6] = bal;
}

// ========== QKV GEMM: 128x128, BK=32, 8 waves, 2-buf, 32 KB LDS (round-17) ==========
__global__ __launch_bounds__(512, 6) void gemm_qkv32(
    const ushort* __restrict__ A0, const ushort* __restrict__ A1, const ushort* __restrict__ A2,
    const ushort* __restrict__ W0, const ushort* __restrict__ W1, const ushort* __restrict__ W2,
    const float* __restrict__ b0, const float* __restrict__ b1, const float* __restrict__ b2,
    ushort* __restrict__ oq, ushort* __restrict__ ok, ushort* __restrict__ ov)
{
  __shared__ __align__(16) ushort lds[2][2][4096];   // [buf][A/W][128 rows x 32 bf16] = 32 KB

  const int nwg = 768;
  int lin = blockIdx.x + (blockIdx.y << 3);
  int swz = (lin & 7) * (nwg >> 3) + (lin >> 3);
  const int z  = swz >> 8;
  const int r_ = swz & 255;
  const int n0 = (r_ & 7) << 7;
  const int m0 = (r_ >> 3) << 7;

  const ushort* __restrict__ A    = (z == 0) ? A0 : (z == 1) ? A1 : A2;
  const ushort* __restrict__ W    = (z == 0) ? W0 : (z == 1) ? W1 : W2;
  const float*  __restrict__ bias = (z == 0) ? b0 : (z == 1) ? b1 : b2;

  const int t = threadIdx.x;
  const int lane = t & 63;
  const int wid = t >> 6;                    // 0..7
  const int wr = wid >> 2, wc = wid & 3;     // 2M x 4N waves; wave tile 64x32
  const int lr = lane & 15, qg = lane >> 4;

  const int srow = t >> 2;
  const int scol = ((((t & 3) - (srow >> 1)) & 3)) << 3;
  auto stage = [&](int buf, int k0) {
    gl_lds16(&A[(size_t)(m0 + srow) * EMBED + k0 + scol], &lds[buf][0][t * 8]);
    gl_lds16(&W[(size_t)(n0 + srow) * EMBED + k0 + scol], &lds[buf][1][t * 8]);
  };

  f32x4 acc[4][2] = {};

  stage(0, 0);
  asm volatile("s_waitcnt vmcnt(0)" ::: "memory");
  __syncthreads();

  for (int kt = 0; kt < 32; ++kt) {
    const int buf = kt & 1;
    if (kt < 31) stage(buf ^ 1, (kt + 1) * 32);

    short8 af[4], bfr[2];
    #pragma unroll
    for (int mi = 0; mi < 4; ++mi) {
      int row = wr * 64 + mi * 16 + lr;
      int sidx = (qg + (row >> 1)) & 3;
      af[mi] = *reinterpret_cast<const short8*>(&lds[buf][0][row * 32 + (sidx << 3)]);
    }
    #pragma unroll
    for (int ni = 0; ni < 2; ++ni) {
      int row = wc * 32 + ni * 16 + lr;
      int sidx = (qg + (row >> 1)) & 3;
      bfr[ni] = *reinterpret_cast<const short8*>(&lds[buf][1][row * 32 + (sidx << 3)]);
    }
    __builtin_amdgcn_s_setprio(1);
    #pragma unroll
    for (int mi = 0; mi < 4; ++mi)
      #pragma unroll
      for (int ni = 0; ni < 2; ++ni)
        acc[mi][ni] = MFMA(af[mi], bfr[ni], acc[mi][ni]);
    __builtin_amdgcn_s_setprio(0);

    if (kt < 31) {
      asm volatile("s_waitcnt vmcnt(0)" ::: "memory");
      __syncthreads();
    }
  }

  // epilogue: bias + layout-specific bf16 store
  #pragma unroll
  for (int ni = 0; ni < 2; ++ni) {
    int ng = n0 + wc * 32 + ni * 16 + lr;
    float bv_ = bias[ng];
    int h = ng >> 6, d = ng & 63;
    #pragma unroll
    for (int mi = 0; mi < 4; ++mi) {
      #pragma unroll
      for (int r = 0; r < 4; ++r) {
        int mg = m0 + wr * 64 + mi * 16 + qg * 4 + r;
        float val = acc[mi][ni][r] + bv_;
        int bb = mg >> 11, s = mg & (SEQ - 1);
        int bh = bb * HEADS + h;
        if (z == 0)
          oq[((size_t)bh * SEQ + s) * HDIM + d] = f2bf(val * QSCALE);
        else if (z == 1)
          ok[((size_t)bh * SEQ + s) * HDIM + d] = f2bf(val);
        else {
          size_t addr = (((size_t)bh * 2 + (d >> 5)) * (SEQ / 32) + (s >> 5)) * 1024
                      + (size_t)(d & 31) * 32 + (s & 31);
          ov[addr] = f2bf(val);
        }
      }
    }
  }
}

// ========== output-proj GEMM: 128x128, BK=64, 8 waves, 2-buf (round-13 best) ==========
__global__ __launch_bounds__(512, 4) void gemm_out128(
    const ushort* __restrict__ A0, const ushort* __restrict__ W0,
    const float* __restrict__ b0, float* __restrict__ of)
{
  __shared__ __align__(16) ushort lds[2][2][8192];   // [buf][A/W][128 x 64 bf16] = 64 KB

  const int nwg = 256;
  int lin = blockIdx.x + (blockIdx.y << 3);
  int swz = (lin & 7) * (nwg >> 3) + (lin >> 3);
  const int r_ = swz & 255;
  const int n0 = (r_ & 7) << 7;
  const int m0 = (r_ >> 3) << 7;

  const ushort* __restrict__ A = A0;
  const ushort* __restrict__ W = W0;
  const float*  __restrict__ bias = b0;

  const int t = threadIdx.x;
  const int lane = t & 63;
  const int wid = t >> 6;                    // 0..7
  const int wr = wid >> 2, wc = wid & 3;     // 2M x 4N waves; wave tile 64x32
  const int lr = lane & 15, qg = lane >> 4;

  auto stage = [&](int buf, int k0) {
    #pragma unroll
    for (int it = 0; it < 2; ++it) {
      int idx = it * 512 + t;
      int row = idx >> 3;
      int col = ((idx & 7) ^ (row & 7)) << 3;
      gl_lds16(&A[(size_t)(m0 + row) * EMBED + k0 + col], &lds[buf][0][idx * 8]);
    }
    #pragma unroll
    for (int it = 0; it < 2; ++it) {
      int idx = it * 512 + t;
      int row = idx >> 3;
      int col = ((idx & 7) ^ (row & 7)) << 3;
      gl_lds16(&W[(size_t)(n0 + row) * EMBED + k0 + col], &lds[buf][1][idx * 8]);
    }
  };

  f32x4 acc[4][2] = {};

  stage(0, 0);
  asm volatile("s_waitcnt vmcnt(0)" ::: "memory");
  __syncthreads();

  for (int kt = 0; kt < 16; ++kt) {
    const int buf = kt & 1;
    if (kt < 15) stage(buf ^ 1, (kt + 1) * 64);

    #pragma unroll
    for (int ks = 0; ks < 2; ++ks) {
      short8 af[4], bfr[2];
      #pragma unroll
      for (int mi = 0; mi < 4; ++mi) {
        int row = wr * 64 + mi * 16 + lr;
        int cp = (ks * 4 + qg) ^ (row & 7);
        af[mi] = *reinterpret_cast<const short8*>(&lds[buf][0][row * 64 + (cp << 3)]);
      }
      #pragma unroll
      for (int ni = 0; ni < 2; ++ni) {
        int row = wc * 32 + ni * 16 + lr;
        int cp = (ks * 4 + qg) ^ (row & 7);
        bfr[ni] = *reinterpret_cast<const short8*>(&lds[buf][1][row * 64 + (cp << 3)]);
      }
      __builtin_amdgcn_s_setprio(1);
      #pragma unroll
      for (int mi = 0; mi < 4; ++mi)
        #pragma unroll
        for (int ni = 0; ni < 2; ++ni)
          acc[mi][ni] = MFMA(af[mi], bfr[ni], acc[mi][ni]);
      __builtin_amdgcn_s_setprio(0);
    }

    if (kt < 15) {
      asm volatile("s_waitcnt vmcnt(0)" ::: "memory");
      __syncthreads();
    }
  }

  #pragma unroll
  for (int ni = 0; ni < 2; ++ni) {
    int ng = n0 + wc * 32 + ni * 16 + lr;
    float bv_ = bias[ng];
    #pragma unroll
    for (int mi = 0; mi < 4; ++mi) {
      #pragma unroll
      for (int r = 0; r < 4; ++r) {
        int mg = m0 + wr * 64 + mi * 16 + qg * 4 + r;
        of[(size_t)mg * EMBED + ng] = acc[mi][ni][r] + bv_;
      }
    }
  }
}

// ================= flash attention v9: v7 + 3-buf counted-vmcnt pipeline =================
// Same 512-block/4-wave structure as v7 (the best measured). Change: 3 K/V buffers
// (24 KB, residency unchanged) with stage(t+2) + vmcnt(2) per step -- tile t+1's K,V
// (always the 2 oldest VMEM ops, possibly after an older mask load; >=3 retire at
// vmcnt(2) in every compiler placement) are guaranteed landed, while tile t+2's 2
// loads stay in flight ACROSS the raw barrier. Loads age ~2 steps (>= L2 latency).
// Buffer (t+2)%3 was last read at step t-1, barrier-separated -> race-free.
__global__ __launch_bounds__(256, 2) void attn(
    const ushort* __restrict__ qws, const ushort* __restrict__ kws,
    const ushort* __restrict__ vws, const unsigned* __restrict__ mbits,
    ushort* __restrict__ xws)
{
  const int t = threadIdx.x;
  const int wid = t >> 6;
  const int l = t & 63;
  const int q31 = l & 31;
  const int h = l >> 5;

  const int L = blockIdx.x;
  const int j = L >> 3;
  const int bh = ((L & 7) << 2) + (j >> 4);   // XCD x owns bh {4x..4x+3}
  const int q0 = (j & 15) << 7;               // 128-row q block
  const int b = bh >> 4, head = bh & 15;

  __shared__ __align__(16) ushort lds[12288];   // 3 bufs x (K 4KB | V 4KB) = 24 KB

  const int qrow = q0 + wid * 32 + q31;
  const ushort* qp = qws + ((size_t)bh * SEQ + qrow) * HDIM + 8 * h;
  short8 qf[4];
  #pragma unroll
  for (int s = 0; s < 4; ++s)
    qf[s] = *reinterpret_cast<const short8*>(qp + 16 * s);

  const int rp = (q31 & 19) | ((q31 & 4) << 1) | ((q31 & 8) >> 1);  // pi(q31)

  int koff[4];
  #pragma unroll
  for (int i = 0; i < 4; ++i)
    koff[i] = rp * 64 + (((h + 2 * i) ^ (rp & 7)) << 3);
  int voff[2][2];
  #pragma unroll
  for (int sb = 0; sb < 2; ++sb)
    #pragma unroll
    for (int jj = 0; jj < 2; ++jj)
      voff[sb][jj] = sb * 1024 + q31 * 32 + (((h + 2 * jj) ^ ((q31 >> 1) & 3)) << 3);

  const ushort* ksb = kws + (size_t)bh * SEQ * HDIM
                    + ((t >> 3) << 6) + (((t & 7) ^ ((t >> 3) & 7)) << 3);
  const int vsub = t >> 7, vd = (t >> 2) & 31, vc = t & 3;
  const ushort* vsb = vws + (((size_t)bh * 2 + vsub) << 16)
                    + vd * 32 + ((vc ^ ((vd >> 1) & 3)) << 3);

  const unsigned* mp = mbits + (size_t)(b * SEQ + qrow) * (SEQ / 32);

  f32x16 accT[2] = {};
  float ls0 = 0.f, ls1 = 0.f, ls2 = 0.f, ls3 = 0.f;

  auto STAGE = [&](int tile, int buf) {
    ushort* base = lds + buf * 4096;
    gl_lds16(ksb + (size_t)tile * 2048, base + t * 8);
    gl_lds16(vsb + (size_t)tile * 1024, base + 2048 + t * 8);
  };

  auto COMP = [&](int bb, unsigned mwc) {
    const ushort* kb = lds + bb;
    const ushort* vb = lds + bb + 2048;
    short8 kf0 = *reinterpret_cast<const short8*>(kb + koff[0]);
    short8 kf1 = *reinterpret_cast<const short8*>(kb + koff[1]);
    short8 kf2 = *reinterpret_cast<const short8*>(kb + koff[2]);
    short8 kf3 = *reinterpret_cast<const short8*>(kb + koff[3]);
    __builtin_amdgcn_s_setprio(1);
    f32x16 s = {};
    s = MFMA32(kf0, qf[0], s);
    s = MFMA32(kf1, qf[1], s);
    s = MFMA32(kf2, qf[2], s);
    s = MFMA32(kf3, qf[3], s);
    __builtin_amdgcn_s_setprio(0);

    short8 vf0 = *reinterpret_cast<const short8*>(vb + voff[0][0]);
    short8 vf1 = *reinterpret_cast<const short8*>(vb + voff[0][1]);
    short8 vf2 = *reinterpret_cast<const short8*>(vb + voff[1][0]);
    short8 vf3 = *reinterpret_cast<const short8*>(vb + voff[1][1]);

    unsigned msh = mwc >> (8 * h);
    union U { unsigned u[4]; short8 s8; } p0u, p1u;
    #pragma unroll
    for (int i = 0; i < 8; ++i) {
      const int r0 = 2 * i, r1 = 2 * i + 1;
      float e0 = ((msh >> ((r0 & 7) + 16 * (r0 >> 3))) & 1u) ? __builtin_amdgcn_exp2f(s[r0]) : 0.0f;
      float e1 = ((msh >> ((r1 & 7) + 16 * (r1 >> 3))) & 1u) ? __builtin_amdgcn_exp2f(s[r1]) : 0.0f;
      if ((i & 3) == 0) ls0 += e0 + e1;
      else if ((i & 3) == 1) ls1 += e0 + e1;
      else if ((i & 3) == 2) ls2 += e0 + e1;
      else ls3 += e0 + e1;
      if (i < 4) p0u.u[i] = cvtpk(e0, e1);
      else       p1u.u[i - 4] = cvtpk(e0, e1);
    }

    __builtin_amdgcn_s_setprio(1);
    accT[0] = MFMA32(vf0, p0u.s8, accT[0]);
    accT[0] = MFMA32(vf1, p1u.s8, accT[0]);
    accT[1] = MFMA32(vf2, p0u.s8, accT[1]);
    accT[1] = MFMA32(vf3, p1u.s8, accT[1]);
    __builtin_amdgcn_s_setprio(0);
  };

  unsigned mw = *mp; ++mp;
  STAGE(0, 0);
  STAGE(1, 1);
  asm volatile("s_waitcnt vmcnt(2)" ::: "memory");   // tile 0's K,V (+mask) landed
  __builtin_amdgcn_s_barrier();
  asm volatile("" ::: "memory");

  #pragma unroll 1
  for (int tile = 0; tile < 64; ++tile) {
    unsigned mn = 0;
    if (tile < 63) { mn = *mp; ++mp; }
    if (tile < 62) STAGE(tile + 2, (tile + 2) % 3);
    COMP((tile % 3) * 4096, mw);
    if (tile < 62)       asm volatile("s_waitcnt vmcnt(2)" ::: "memory");
    else if (tile == 62) asm volatile("s_waitcnt vmcnt(0)" ::: "memory");
    if (tile < 63) {
      __builtin_amdgcn_s_barrier();
      asm volatile("" ::: "memory");
    }
    mw = mn;
  }
  __syncthreads();   // epilogue xb aliases buffers read in the last COMP

  float lsum = (ls0 + ls1) + (ls2 + ls3);
  float lrow = lsum + __shfl_xor(lsum, 32);
  float inv = 1.0f / lrow;

  ushort* xb = lds + wid * 2304;   // [32][72] per wave
  #pragma unroll
  for (int nb = 0; nb < 2; ++nb)
    #pragma unroll
    for (int rg = 0; rg < 4; ++rg) {
      int dbase = 32 * nb + 8 * rg + 4 * h;
      uint2 pk = make_uint2(
          packbf(accT[nb][4 * rg] * inv,     accT[nb][4 * rg + 1] * inv),
          packbf(accT[nb][4 * rg + 2] * inv, accT[nb][4 * rg + 3] * inv));
      *reinterpret_cast<uint2*>(&xb[q31 * 72 + dbase]) = pk;
    }
  asm volatile("" ::: "memory");   // same-wave LDS order
  #pragma unroll
  for (int pp = 0; pp < 4; ++pp) {
    int row = pp * 8 + (l >> 3);
    int col = (l & 7) * 8;
    short8 xv = *reinterpret_cast<const short8*>(&xb[row * 72 + col]);
    *reinterpret_cast<short8*>(
        &xws[((size_t)b * SEQ + q0 + wid * 32 + row) * EMBED + head * HDIM + col]) = xv;
  }
}

// ================= launch =================
extern "C" void kernel_launch(void* const* d_in, const int* in_sizes, int n_in,
                              void* d_out, int out_size, void* d_ws, size_t ws_size,
                              hipStream_t stream) {
  (void)in_sizes; (void)n_in; (void)out_size; (void)ws_size;
  const float* query = (const float*)d_in[0];
  const float* key   = (const float*)d_in[1];
  const float* value = (const float*)d_in[2];
  const int*   mask  = (const int*)d_in[3];
  const float* Wq = (const float*)d_in[4];  const float* bq = (const float*)d_in[5];
  const float* Wk = (const float*)d_in[6];  const float* bk = (const float*)d_in[7];
  const float* Wv = (const float*)d_in[8];  const float* bv = (const float*)d_in[9];
  const float* Wo = (const float*)d_in[10]; const float* bo = (const float*)d_in[11];
  float* out = (float*)d_out;

  const size_t NQKV = (size_t)BATCH * HEADS * SEQ * HDIM;   // 4,194,304
  const size_t NW   = (size_t)EMBED * EMBED;                // 1,048,576
  ushort* qws = (ushort*)d_ws;
  ushort* kws = qws + NQKV;
  ushort* vws = kws + NQKV;
  ushort* xws = vws + NQKV;
  unsigned* mbits = (unsigned*)(xws + NQKV);                // 1 MB packed mask
  ushort* aqb = (ushort*)(mbits + (size_t)BATCH * SEQ * SEQ / 32);
  ushort* akb = aqb + NQKV;
  ushort* avb = akb + NQKV;
  ushort* wqb = avb + NQKV;
  ushort* wkb = wqb + NW;
  ushort* wvb = wkb + NW;
  ushort* wob = wvb + NW;

  tobf16<<<dim3((NQKV / 8 + 255) / 256, 1, 7), 256, 0, stream>>>(
      query, key, value, Wq, Wk, Wv, Wo, aqb, akb, avb, wqb, wkb, wvb, wob);

  maskpack<<<(BATCH * SEQ * SEQ) / 256, 256, 0, stream>>>(mask, (unsigned long long*)mbits);

  gemm_qkv32<<<dim3(8, 96), 512, 0, stream>>>(
      aqb, akb, avb, wqb, wkb, wvb, bq, bk, bv, qws, kws, vws);

  attn<<<dim3(512), 256, 0, stream>>>(qws, kws, vws, mbits, xws);

  gemm_out128<<<dim3(8, 32), 512, 0, stream>>>(xws, wob, bo, out);
}

// Round 20
// 151.898 us; speedup vs baseline: 1.0666x; 1.0666x over previous
//
#include <hip/hip_runtime.h>

// ---------------- problem constants ----------------
#define EMBED 1024
#define HEADS 16
#define HDIM  64
#define BATCH 2
#define SEQ   2048
#define MTOT  (BATCH*SEQ)          // 4096 rows in all GEMMs
#define LOG2E 1.4426950408889634f
#define QSCALE (0.125f * LOG2E)    // head_dim^-0.5 * log2(e), folded into q

typedef __attribute__((ext_vector_type(8)))  short short8;   // 8 bf16 (4 VGPR)
typedef __attribute__((ext_vector_type(4)))  float f32x4;
typedef __attribute__((ext_vector_type(16))) float f32x16;

#define MFMA(a,b,c)   __builtin_amdgcn_mfma_f32_16x16x32_bf16(a,b,c,0,0,0)
#define MFMA32(a,b,c) __builtin_amdgcn_mfma_f32_32x32x16_bf16(a,b,c,0,0,0)

__device__ __forceinline__ ushort f2bf(float f) {
  union { float f; unsigned u; } v; v.f = f;
  unsigned u = v.u;
  unsigned r = u + 0x7fffu + ((u >> 16) & 1u);   // round-to-nearest-even
  return (ushort)(r >> 16);
}
__device__ __forceinline__ unsigned packbf(float a, float b) {
  return (unsigned)f2bf(a) | ((unsigned)f2bf(b) << 16);
}
// hw packed f32x2 -> bf16x2 (single instruction)
__device__ __forceinline__ unsigned cvtpk(float lo, float hi) {
  unsigned r;
  asm("v_cvt_pk_bf16_f32 %0, %1, %2" : "=v"(r) : "v"(lo), "v"(hi));
  return r;
}
__device__ __forceinline__ uint2 cvt4(float4 v) {
  uint2 r;
  asm("v_cvt_pk_bf16_f32 %0, %2, %3\n\t"
      "v_cvt_pk_bf16_f32 %1, %4, %5"
      : "=&v"(r.x), "=&v"(r.y)
      : "v"(v.x), "v"(v.y), "v"(v.z), "v"(v.w));
  return r;
}
// async global->LDS, 16 B per lane (wave-uniform LDS base + lane*16)
__device__ __forceinline__ void gl_lds16(const ushort* g, ushort* l) {
  __builtin_amdgcn_global_load_lds(
      (const __attribute__((address_space(1))) unsigned*)g,
      (__attribute__((address_space(3))) unsigned*)l, 16, 0, 0);
}

// ================= fp32 -> bf16 convert (inputs + weights, once) =================
__global__ __launch_bounds__(256) void tobf16(
    const float* __restrict__ s0, const float* __restrict__ s1, const float* __restrict__ s2,
    const float* __restrict__ s3, const float* __restrict__ s4, const float* __restrict__ s5,
    const float* __restrict__ s6,
    ushort* __restrict__ d0, ushort* __restrict__ d1, ushort* __restrict__ d2,
    ushort* __restrict__ d3, ushort* __restrict__ d4, ushort* __restrict__ d5,
    ushort* __restrict__ d6)
{
  const int z = blockIdx.z;
  const float* s; ushort* d;
  switch (z) {
    case 0: s = s0; d = d0; break;
    case 1: s = s1; d = d1; break;
    case 2: s = s2; d = d2; break;
    case 3: s = s3; d = d3; break;
    case 4: s = s4; d = d4; break;
    case 5: s = s5; d = d5; break;
    default: s = s6; d = d6; break;
  }
  const int nch = (z < 3) ? (MTOT * EMBED / 8) : (EMBED * EMBED / 8);
  int i = blockIdx.x * 256 + threadIdx.x;
  if (i >= nch) return;
  float4 a = reinterpret_cast<const float4*>(s)[2 * i];
  float4 b = reinterpret_cast<const float4*>(s)[2 * i + 1];
  uint2 lo = cvt4(a), hi = cvt4(b);
  reinterpret_cast<uint4*>(d)[i] = make_uint4(lo.x, lo.y, hi.x, hi.y);
}

// ================= mask bit-pack =================
__global__ __launch_bounds__(256) void maskpack(const int* __restrict__ mask,
                                                unsigned long long* __restrict__ bits) {
  size_t idx = (size_t)blockIdx.x * 256 + threadIdx.x;
  unsigned long long bal = __ballot(mask[idx] != 0);
  if ((threadIdx.x & 63) == 0) bits[idx >> 6] = bal;
}

// ========== QKV GEMM: 128x128, BK=32, 8 waves, 2-buf, 32 KB LDS (round-17) ==========
__global__ __launch_bounds__(512, 6) void gemm_qkv32(
    const ushort* __restrict__ A0, const ushort* __restrict__ A1, const ushort* __restrict__ A2,
    const ushort* __restrict__ W0, const ushort* __restrict__ W1, const ushort* __restrict__ W2,
    const float* __restrict__ b0, const float* __restrict__ b1, const float* __restrict__ b2,
    ushort* __restrict__ oq, ushort* __restrict__ ok, ushort* __restrict__ ov)
{
  __shared__ __align__(16) ushort lds[2][2][4096];   // [buf][A/W][128 rows x 32 bf16] = 32 KB

  const int nwg = 768;
  int lin = blockIdx.x + (blockIdx.y << 3);
  int swz = (lin & 7) * (nwg >> 3) + (lin >> 3);
  const int z  = swz >> 8;
  const int r_ = swz & 255;
  const int n0 = (r_ & 7) << 7;
  const int m0 = (r_ >> 3) << 7;

  const ushort* __restrict__ A    = (z == 0) ? A0 : (z == 1) ? A1 : A2;
  const ushort* __restrict__ W    = (z == 0) ? W0 : (z == 1) ? W1 : W2;
  const float*  __restrict__ bias = (z == 0) ? b0 : (z == 1) ? b1 : b2;

  const int t = threadIdx.x;
  const int lane = t & 63;
  const int wid = t >> 6;                    // 0..7
  const int wr = wid >> 2, wc = wid & 3;     // 2M x 4N waves; wave tile 64x32
  const int lr = lane & 15, qg = lane >> 4;

  const int srow = t >> 2;
  const int scol = ((((t & 3) - (srow >> 1)) & 3)) << 3;
  auto stage = [&](int buf, int k0) {
    gl_lds16(&A[(size_t)(m0 + srow) * EMBED + k0 + scol], &lds[buf][0][t * 8]);
    gl_lds16(&W[(size_t)(n0 + srow) * EMBED + k0 + scol], &lds[buf][1][t * 8]);
  };

  f32x4 acc[4][2] = {};

  stage(0, 0);
  asm volatile("s_waitcnt vmcnt(0)" ::: "memory");
  __syncthreads();

  for (int kt = 0; kt < 32; ++kt) {
    const int buf = kt & 1;
    if (kt < 31) stage(buf ^ 1, (kt + 1) * 32);

    short8 af[4], bfr[2];
    #pragma unroll
    for (int mi = 0; mi < 4; ++mi) {
      int row = wr * 64 + mi * 16 + lr;
      int sidx = (qg + (row >> 1)) & 3;
      af[mi] = *reinterpret_cast<const short8*>(&lds[buf][0][row * 32 + (sidx << 3)]);
    }
    #pragma unroll
    for (int ni = 0; ni < 2; ++ni) {
      int row = wc * 32 + ni * 16 + lr;
      int sidx = (qg + (row >> 1)) & 3;
      bfr[ni] = *reinterpret_cast<const short8*>(&lds[buf][1][row * 32 + (sidx << 3)]);
    }
    __builtin_amdgcn_s_setprio(1);
    #pragma unroll
    for (int mi = 0; mi < 4; ++mi)
      #pragma unroll
      for (int ni = 0; ni < 2; ++ni)
        acc[mi][ni] = MFMA(af[mi], bfr[ni], acc[mi][ni]);
    __builtin_amdgcn_s_setprio(0);

    if (kt < 31) {
      asm volatile("s_waitcnt vmcnt(0)" ::: "memory");
      __syncthreads();
    }
  }

  // epilogue: bias + layout-specific bf16 store
  #pragma unroll
  for (int ni = 0; ni < 2; ++ni) {
    int ng = n0 + wc * 32 + ni * 16 + lr;
    float bv_ = bias[ng];
    int h = ng >> 6, d = ng & 63;
    #pragma unroll
    for (int mi = 0; mi < 4; ++mi) {
      #pragma unroll
      for (int r = 0; r < 4; ++r) {
        int mg = m0 + wr * 64 + mi * 16 + qg * 4 + r;
        float val = acc[mi][ni][r] + bv_;
        int bb = mg >> 11, s = mg & (SEQ - 1);
        int bh = bb * HEADS + h;
        if (z == 0)
          oq[((size_t)bh * SEQ + s) * HDIM + d] = f2bf(val * QSCALE);
        else if (z == 1)
          ok[((size_t)bh * SEQ + s) * HDIM + d] = f2bf(val);
        else {
          size_t addr = (((size_t)bh * 2 + (d >> 5)) * (SEQ / 32) + (s >> 5)) * 1024
                      + (size_t)(d & 31) * 32 + (s & 31);
          ov[addr] = f2bf(val);
        }
      }
    }
  }
}

// ========== output-proj GEMM: 128x128, BK=64, 8 waves, 2-buf (round-13 best) ==========
__global__ __launch_bounds__(512, 4) void gemm_out128(
    const ushort* __restrict__ A0, const ushort* __restrict__ W0,
    const float* __restrict__ b0, float* __restrict__ of)
{
  __shared__ __align__(16) ushort lds[2][2][8192];   // [buf][A/W][128 x 64 bf16] = 64 KB

  const int nwg = 256;
  int lin = blockIdx.x + (blockIdx.y << 3);
  int swz = (lin & 7) * (nwg >> 3) + (lin >> 3);
  const int r_ = swz & 255;
  const int n0 = (r_ & 7) << 7;
  const int m0 = (r_ >> 3) << 7;

  const ushort* __restrict__ A = A0;
  const ushort* __restrict__ W = W0;
  const float*  __restrict__ bias = b0;

  const int t = threadIdx.x;
  const int lane = t & 63;
  const int wid = t >> 6;                    // 0..7
  const int wr = wid >> 2, wc = wid & 3;     // 2M x 4N waves; wave tile 64x32
  const int lr = lane & 15, qg = lane >> 4;

  auto stage = [&](int buf, int k0) {
    #pragma unroll
    for (int it = 0; it < 2; ++it) {
      int idx = it * 512 + t;
      int row = idx >> 3;
      int col = ((idx & 7) ^ (row & 7)) << 3;
      gl_lds16(&A[(size_t)(m0 + row) * EMBED + k0 + col], &lds[buf][0][idx * 8]);
    }
    #pragma unroll
    for (int it = 0; it < 2; ++it) {
      int idx = it * 512 + t;
      int row = idx >> 3;
      int col = ((idx & 7) ^ (row & 7)) << 3;
      gl_lds16(&W[(size_t)(n0 + row) * EMBED + k0 + col], &lds[buf][1][idx * 8]);
    }
  };

  f32x4 acc[4][2] = {};

  stage(0, 0);
  asm volatile("s_waitcnt vmcnt(0)" ::: "memory");
  __syncthreads();

  for (int kt = 0; kt < 16; ++kt) {
    const int buf = kt & 1;
    if (kt < 15) stage(buf ^ 1, (kt + 1) * 64);

    #pragma unroll
    for (int ks = 0; ks < 2; ++ks) {
      short8 af[4], bfr[2];
      #pragma unroll
      for (int mi = 0; mi < 4; ++mi) {
        int row = wr * 64 + mi * 16 + lr;
        int cp = (ks * 4 + qg) ^ (row & 7);
        af[mi] = *reinterpret_cast<const short8*>(&lds[buf][0][row * 64 + (cp << 3)]);
      }
      #pragma unroll
      for (int ni = 0; ni < 2; ++ni) {
        int row = wc * 32 + ni * 16 + lr;
        int cp = (ks * 4 + qg) ^ (row & 7);
        bfr[ni] = *reinterpret_cast<const short8*>(&lds[buf][1][row * 64 + (cp << 3)]);
      }
      __builtin_amdgcn_s_setprio(1);
      #pragma unroll
      for (int mi = 0; mi < 4; ++mi)
        #pragma unroll
        for (int ni = 0; ni < 2; ++ni)
          acc[mi][ni] = MFMA(af[mi], bfr[ni], acc[mi][ni]);
      __builtin_amdgcn_s_setprio(0);
    }

    if (kt < 15) {
      asm volatile("s_waitcnt vmcnt(0)" ::: "memory");
      __syncthreads();
    }
  }

  #pragma unroll
  for (int ni = 0; ni < 2; ++ni) {
    int ng = n0 + wc * 32 + ni * 16 + lr;
    float bv_ = bias[ng];
    #pragma unroll
    for (int mi = 0; mi < 4; ++mi) {
      #pragma unroll
      for (int r = 0; r < 4; ++r) {
        int mg = m0 + wr * 64 + mi * 16 + qg * 4 + r;
        of[(size_t)mg * EMBED + ng] = acc[mi][ni][r] + bv_;
      }
    }
  }
}

// ================= flash attention v10: v7 with KVBLK=64 (half the barriers) =================
// Same 512-block/4-wave drain structure as v7 (best measured). Step now covers 64 kv:
// stage 16 KB (K[64][64] + V 2 tile-pairs), 8 QK^T + 8 PV MFMA32, 32 exp2, ONE
// vmcnt(0)+barrier -> 32 steps instead of 64 (fixed per-step cost halved).
// K rows rp and rp+32 use the same XOR since (rp+32)&7 == rp&7.
__global__ __launch_bounds__(256, 2) void attn(
    const ushort* __restrict__ qws, const ushort* __restrict__ kws,
    const ushort* __restrict__ vws, const unsigned* __restrict__ mbits,
    ushort* __restrict__ xws)
{
  const int t = threadIdx.x;
  const int wid = t >> 6;
  const int l = t & 63;
  const int q31 = l & 31;
  const int h = l >> 5;

  const int L = blockIdx.x;
  const int j = L >> 3;
  const int bh = ((L & 7) << 2) + (j >> 4);   // XCD x owns bh {4x..4x+3}
  const int q0 = (j & 15) << 7;               // 128-row q block
  const int b = bh >> 4, head = bh & 15;

  // buf = [K 4096 ush][Vtile0 2048][Vtile1 2048] = 8192 ush (16 KB); 2 bufs = 32 KB
  __shared__ __align__(16) ushort lds[16384];

  const int qrow = q0 + wid * 32 + q31;
  const ushort* qp = qws + ((size_t)bh * SEQ + qrow) * HDIM + 8 * h;
  short8 qf[4];
  #pragma unroll
  for (int s = 0; s < 4; ++s)
    qf[s] = *reinterpret_cast<const short8*>(qp + 16 * s);

  const int rp = (q31 & 19) | ((q31 & 4) << 1) | ((q31 & 8) >> 1);  // pi(q31)

  int koff[4];
  #pragma unroll
  for (int i = 0; i < 4; ++i)
    koff[i] = rp * 64 + (((h + 2 * i) ^ (rp & 7)) << 3);
  int voff[2][2];
  #pragma unroll
  for (int sb = 0; sb < 2; ++sb)
    #pragma unroll
    for (int jj = 0; jj < 2; ++jj)
      voff[sb][jj] = sb * 1024 + q31 * 32 + (((h + 2 * jj) ^ ((q31 >> 1) & 3)) << 3);

  // staging sources: K 2 chunks/thread (rows 0..63), V 2 chunks/thread (2 s-tiles)
  const ushort* ksb[2];
  #pragma unroll
  for (int it = 0; it < 2; ++it) {
    int idx = it * 256 + t;
    int krow = idx >> 3, kslot = idx & 7;
    ksb[it] = kws + (size_t)bh * SEQ * HDIM + krow * 64 + ((kslot ^ (krow & 7)) << 3);
  }
  const int vsub = t >> 7, vd = (t >> 2) & 31, vc = t & 3;
  const ushort* vsb = vws + (((size_t)bh * 2 + vsub) << 16)
                    + vd * 32 + ((vc ^ ((vd >> 1) & 3)) << 3);

  const unsigned* mp = mbits + (size_t)(b * SEQ + qrow) * (SEQ / 32);

  f32x16 accT[2] = {};
  float ls0 = 0.f, ls1 = 0.f, ls2 = 0.f, ls3 = 0.f;

  // stage one 64-kv step into buf bb (ushort offset 0 or 8192)
  auto STAGE = [&](int step, int bb) {
    ushort* base = lds + bb;
    #pragma unroll
    for (int it = 0; it < 2; ++it)
      gl_lds16(ksb[it] + (size_t)step * 4096, base + (it * 256 + t) * 8);
    gl_lds16(vsb + (size_t)(2 * step) * 1024,     base + 4096 + t * 8);
    gl_lds16(vsb + (size_t)(2 * step + 1) * 1024, base + 6144 + t * 8);
  };

  auto SOFTMAX16 = [&](const f32x16& s, unsigned msh,
                       short8& pa, short8& pb) {
    union U { unsigned u[4]; short8 s8; } p0u, p1u;
    #pragma unroll
    for (int i = 0; i < 8; ++i) {
      const int r0 = 2 * i, r1 = 2 * i + 1;
      float e0 = ((msh >> ((r0 & 7) + 16 * (r0 >> 3))) & 1u) ? __builtin_amdgcn_exp2f(s[r0]) : 0.0f;
      float e1 = ((msh >> ((r1 & 7) + 16 * (r1 >> 3))) & 1u) ? __builtin_amdgcn_exp2f(s[r1]) : 0.0f;
      if ((i & 3) == 0) ls0 += e0 + e1;
      else if ((i & 3) == 1) ls1 += e0 + e1;
      else if ((i & 3) == 2) ls2 += e0 + e1;
      else ls3 += e0 + e1;
      if (i < 4) p0u.u[i] = cvtpk(e0, e1);
      else       p1u.u[i - 4] = cvtpk(e0, e1);
    }
    pa = p0u.s8; pb = p1u.s8;
  };

  auto COMP = [&](int bb, unsigned mw0, unsigned mw1) {
    const ushort* kb = lds + bb;
    const ushort* vb = lds + bb + 4096;
    // QK^T group A (kv rows 0..31 of the step) and B (rows 32..63)
    short8 kfa0 = *reinterpret_cast<const short8*>(kb + koff[0]);
    short8 kfa1 = *reinterpret_cast<const short8*>(kb + koff[1]);
    short8 kfa2 = *reinterpret_cast<const short8*>(kb + koff[2]);
    short8 kfa3 = *reinterpret_cast<const short8*>(kb + koff[3]);
    short8 kfb0 = *reinterpret_cast<const short8*>(kb + koff[0] + 2048);
    short8 kfb1 = *reinterpret_cast<const short8*>(kb + koff[1] + 2048);
    short8 kfb2 = *reinterpret_cast<const short8*>(kb + koff[2] + 2048);
    short8 kfb3 = *reinterpret_cast<const short8*>(kb + koff[3] + 2048);
    __builtin_amdgcn_s_setprio(1);
    f32x16 sa = {}, sb = {};
    sa = MFMA32(kfa0, qf[0], sa);
    sa = MFMA32(kfa1, qf[1], sa);
    sa = MFMA32(kfa2, qf[2], sa);
    sa = MFMA32(kfa3, qf[3], sa);
    sb = MFMA32(kfb0, qf[0], sb);
    sb = MFMA32(kfb1, qf[1], sb);
    sb = MFMA32(kfb2, qf[2], sb);
    sb = MFMA32(kfb3, qf[3], sb);
    __builtin_amdgcn_s_setprio(0);

    short8 vf0a = *reinterpret_cast<const short8*>(vb + voff[0][0]);
    short8 vf1a = *reinterpret_cast<const short8*>(vb + voff[0][1]);
    short8 vf2a = *reinterpret_cast<const short8*>(vb + voff[1][0]);
    short8 vf3a = *reinterpret_cast<const short8*>(vb + voff[1][1]);
    short8 vf0b = *reinterpret_cast<const short8*>(vb + 2048 + voff[0][0]);
    short8 vf1b = *reinterpret_cast<const short8*>(vb + 2048 + voff[0][1]);
    short8 vf2b = *reinterpret_cast<const short8*>(vb + 2048 + voff[1][0]);
    short8 vf3b = *reinterpret_cast<const short8*>(vb + 2048 + voff[1][1]);

    short8 pa0, pa1, pb0, pb1;
    SOFTMAX16(sa, mw0 >> (8 * h), pa0, pa1);
    SOFTMAX16(sb, mw1 >> (8 * h), pb0, pb1);

    __builtin_amdgcn_s_setprio(1);
    accT[0] = MFMA32(vf0a, pa0, accT[0]);
    accT[0] = MFMA32(vf1a, pa1, accT[0]);
    accT[1] = MFMA32(vf2a, pa0, accT[1]);
    accT[1] = MFMA32(vf3a, pa1, accT[1]);
    accT[0] = MFMA32(vf0b, pb0, accT[0]);
    accT[0] = MFMA32(vf1b, pb1, accT[0]);
    accT[1] = MFMA32(vf2b, pb0, accT[1]);
    accT[1] = MFMA32(vf3b, pb1, accT[1]);
    __builtin_amdgcn_s_setprio(0);
  };

  unsigned mw0 = mp[0], mw1 = mp[1]; mp += 2;
  STAGE(0, 0);
  asm volatile("s_waitcnt vmcnt(0)" ::: "memory");
  __syncthreads();

  #pragma unroll 1
  for (int it = 0; it < 16; ++it) {
    // step A: compute buf0, stage step 2it+1 -> buf1
    STAGE(2 * it + 1, 8192);
    unsigned mn0 = mp[0], mn1 = mp[1]; mp += 2;
    COMP(0, mw0, mw1);
    asm volatile("s_waitcnt vmcnt(0)" ::: "memory");
    __syncthreads();
    mw0 = mn0; mw1 = mn1;
    // step B: compute buf1, stage step 2it+2 -> buf0
    if (it < 15) STAGE(2 * it + 2, 0);
    mn0 = mp[0]; mn1 = mp[1]; mp += 2;
    COMP(8192, mw0, mw1);
    asm volatile("s_waitcnt vmcnt(0)" ::: "memory");
    __syncthreads();
    mw0 = mn0; mw1 = mn1;
  }

  float lsum = (ls0 + ls1) + (ls2 + ls3);
  float lrow = lsum + __shfl_xor(lsum, 32);
  float inv = 1.0f / lrow;

  ushort* xb = lds + wid * 2304;   // [32][72] per wave
  #pragma unroll
  for (int nb = 0; nb < 2; ++nb)
    #pragma unroll
    for (int rg = 0; rg < 4; ++rg) {
      int dbase = 32 * nb + 8 * rg + 4 * h;
      uint2 pk = make_uint2(
          packbf(accT[nb][4 * rg] * inv,     accT[nb][4 * rg + 1] * inv),
          packbf(accT[nb][4 * rg + 2] * inv, accT[nb][4 * rg + 3] * inv));
      *reinterpret_cast<uint2*>(&xb[q31 * 72 + dbase]) = pk;
    }
  asm volatile("" ::: "memory");   // same-wave LDS order
  #pragma unroll
  for (int pp = 0; pp < 4; ++pp) {
    int row = pp * 8 + (l >> 3);
    int col = (l & 7) * 8;
    short8 xv = *reinterpret_cast<const short8*>(&xb[row * 72 + col]);
    *reinterpret_cast<short8*>(
        &xws[((size_t)b * SEQ + q0 + wid * 32 + row) * EMBED + head * HDIM + col]) = xv;
  }
}

// ================= launch =================
extern "C" void kernel_launch(void* const* d_in, const int* in_sizes, int n_in,
                              void* d_out, int out_size, void* d_ws, size_t ws_size,
                              hipStream_t stream) {
  (void)in_sizes; (void)n_in; (void)out_size; (void)ws_size;
  const float* query = (const float*)d_in[0];
  const float* key   = (const float*)d_in[1];
  const float* value = (const float*)d_in[2];
  const int*   mask  = (const int*)d_in[3];
  const float* Wq = (const float*)d_in[4];  const float* bq = (const float*)d_in[5];
  const float* Wk = (const float*)d_in[6];  const float* bk = (const float*)d_in[7];
  const float* Wv = (const float*)d_in[8];  const float* bv = (const float*)d_in[9];
  const float* Wo = (const float*)d_in[10]; const float* bo = (const float*)d_in[11];
  float* out = (float*)d_out;

  const size_t NQKV = (size_t)BATCH * HEADS * SEQ * HDIM;   // 4,194,304
  const size_t NW   = (size_t)EMBED * EMBED;                // 1,048,576
  ushort* qws = (ushort*)d_ws;
  ushort* kws = qws + NQKV;
  ushort* vws = kws + NQKV;
  ushort* xws = vws + NQKV;
  unsigned* mbits = (unsigned*)(xws + NQKV);                // 1 MB packed mask
  ushort* aqb = (ushort*)(mbits + (size_t)BATCH * SEQ * SEQ / 32);
  ushort* akb = aqb + NQKV;
  ushort* avb = akb + NQKV;
  ushort* wqb = avb + NQKV;
  ushort* wkb = wqb + NW;
  ushort* wvb = wkb + NW;
  ushort* wob = wvb + NW;

  tobf16<<<dim3((NQKV / 8 + 255) / 256, 1, 7), 256, 0, stream>>>(
      query, key, value, Wq, Wk, Wv, Wo, aqb, akb, avb, wqb, wkb, wvb, wob);

  maskpack<<<(BATCH * SEQ * SEQ) / 256, 256, 0, stream>>>(mask, (unsigned long long*)mbits);

  gemm_qkv32<<<dim3(8, 96), 512, 0, stream>>>(
      aqb, akb, avb, wqb, wkb, wvb, bq, bk, bv, qws, kws, vws);

  attn<<<dim3(512), 256, 0, stream>>>(qws, kws, vws, mbits, xws);

  gemm_out128<<<dim3(8, 32), 512, 0, stream>>>(xws, wob, bo, out);
}

// Round 21
// 142.834 us; speedup vs baseline: 1.1343x; 1.0635x over previous
//
#include <hip/hip_runtime.h>

// ---------------- problem constants ----------------
#define EMBED 1024
#define HEADS 16
#define HDIM  64
#define BATCH 2
#define SEQ   2048
#define MTOT  (BATCH*SEQ)          // 4096 rows in all GEMMs
#define LOG2E 1.4426950408889634f
#define QSCALE (0.125f * LOG2E)    // head_dim^-0.5 * log2(e), folded into q

typedef __attribute__((ext_vector_type(8)))  short short8;   // 8 bf16 (4 VGPR)
typedef __attribute__((ext_vector_type(4)))  float f32x4;
typedef __attribute__((ext_vector_type(16))) float f32x16;

#define MFMA(a,b,c)   __builtin_amdgcn_mfma_f32_16x16x32_bf16(a,b,c,0,0,0)
#define MFMA32(a,b,c) __builtin_amdgcn_mfma_f32_32x32x16_bf16(a,b,c,0,0,0)

__device__ __forceinline__ ushort f2bf(float f) {
  union { float f; unsigned u; } v; v.f = f;
  unsigned u = v.u;
  unsigned r = u + 0x7fffu + ((u >> 16) & 1u);   // round-to-nearest-even
  return (ushort)(r >> 16);
}
__device__ __forceinline__ unsigned packbf(float a, float b) {
  return (unsigned)f2bf(a) | ((unsigned)f2bf(b) << 16);
}
// hw packed f32x2 -> bf16x2 (single instruction)
__device__ __forceinline__ unsigned cvtpk(float lo, float hi) {
  unsigned r;
  asm("v_cvt_pk_bf16_f32 %0, %1, %2" : "=v"(r) : "v"(lo), "v"(hi));
  return r;
}
__device__ __forceinline__ uint2 cvt4(float4 v) {
  uint2 r;
  asm("v_cvt_pk_bf16_f32 %0, %2, %3\n\t"
      "v_cvt_pk_bf16_f32 %1, %4, %5"
      : "=&v"(r.x), "=&v"(r.y)
      : "v"(v.x), "v"(v.y), "v"(v.z), "v"(v.w));
  return r;
}
// async global->LDS, 16 B per lane (wave-uniform LDS base + lane*16)
__device__ __forceinline__ void gl_lds16(const ushort* g, ushort* l) {
  __builtin_amdgcn_global_load_lds(
      (const __attribute__((address_space(1))) unsigned*)g,
      (__attribute__((address_space(3))) unsigned*)l, 16, 0, 0);
}

// ============ fused prep: fp32->bf16 convert (z=0..6) + mask bit-pack (z=7) ============
__global__ __launch_bounds__(256) void prep(
    const float* __restrict__ s0, const float* __restrict__ s1, const float* __restrict__ s2,
    const float* __restrict__ s3, const float* __restrict__ s4, const float* __restrict__ s5,
    const float* __restrict__ s6, const int* __restrict__ mask,
    ushort* __restrict__ d0, ushort* __restrict__ d1, ushort* __restrict__ d2,
    ushort* __restrict__ d3, ushort* __restrict__ d4, ushort* __restrict__ d5,
    ushort* __restrict__ d6, ushort* __restrict__ mbits16)
{
  const int z = blockIdx.z;
  if (z == 7) {
    // pack 16 mask ints -> 1 ushort per thread (coalesced both sides)
    size_t i16 = ((size_t)blockIdx.x * 256 + threadIdx.x);
    if (i16 >= (size_t)BATCH * SEQ * SEQ / 16) return;
    const int4* m4 = reinterpret_cast<const int4*>(mask + i16 * 16);
    unsigned bits = 0;
    #pragma unroll
    for (int k = 0; k < 4; ++k) {
      int4 v = m4[k];
      bits |= (unsigned)(v.x != 0) << (4 * k);
      bits |= (unsigned)(v.y != 0) << (4 * k + 1);
      bits |= (unsigned)(v.z != 0) << (4 * k + 2);
      bits |= (unsigned)(v.w != 0) << (4 * k + 3);
    }
    mbits16[i16] = (ushort)bits;
    return;
  }
  const float* s; ushort* d;
  switch (z) {
    case 0: s = s0; d = d0; break;
    case 1: s = s1; d = d1; break;
    case 2: s = s2; d = d2; break;
    case 3: s = s3; d = d3; break;
    case 4: s = s4; d = d4; break;
    case 5: s = s5; d = d5; break;
    default: s = s6; d = d6; break;
  }
  const int nch = (z < 3) ? (MTOT * EMBED / 8) : (EMBED * EMBED / 8);
  int i = blockIdx.x * 256 + threadIdx.x;
  if (i >= nch) return;
  float4 a = reinterpret_cast<const float4*>(s)[2 * i];
  float4 b = reinterpret_cast<const float4*>(s)[2 * i + 1];
  uint2 lo = cvt4(a), hi = cvt4(b);
  reinterpret_cast<uint4*>(d)[i] = make_uint4(lo.x, lo.y, hi.x, hi.y);
}

// ========== QKV GEMM: 128x128, BK=32, 8 waves, 2-buf, 32 KB LDS (round-17 best) ==========
__global__ __launch_bounds__(512, 6) void gemm_qkv32(
    const ushort* __restrict__ A0, const ushort* __restrict__ A1, const ushort* __restrict__ A2,
    const ushort* __restrict__ W0, const ushort* __restrict__ W1, const ushort* __restrict__ W2,
    const float* __restrict__ b0, const float* __restrict__ b1, const float* __restrict__ b2,
    ushort* __restrict__ oq, ushort* __restrict__ ok, ushort* __restrict__ ov)
{
  __shared__ __align__(16) ushort lds[2][2][4096];   // [buf][A/W][128 rows x 32 bf16] = 32 KB

  const int nwg = 768;
  int lin = blockIdx.x + (blockIdx.y << 3);
  int swz = (lin & 7) * (nwg >> 3) + (lin >> 3);
  const int z  = swz >> 8;
  const int r_ = swz & 255;
  const int n0 = (r_ & 7) << 7;
  const int m0 = (r_ >> 3) << 7;

  const ushort* __restrict__ A    = (z == 0) ? A0 : (z == 1) ? A1 : A2;
  const ushort* __restrict__ W    = (z == 0) ? W0 : (z == 1) ? W1 : W2;
  const float*  __restrict__ bias = (z == 0) ? b0 : (z == 1) ? b1 : b2;

  const int t = threadIdx.x;
  const int lane = t & 63;
  const int wid = t >> 6;                    // 0..7
  const int wr = wid >> 2, wc = wid & 3;     // 2M x 4N waves; wave tile 64x32
  const int lr = lane & 15, qg = lane >> 4;

  const int srow = t >> 2;
  const int scol = ((((t & 3) - (srow >> 1)) & 3)) << 3;
  auto stage = [&](int buf, int k0) {
    gl_lds16(&A[(size_t)(m0 + srow) * EMBED + k0 + scol], &lds[buf][0][t * 8]);
    gl_lds16(&W[(size_t)(n0 + srow) * EMBED + k0 + scol], &lds[buf][1][t * 8]);
  };

  f32x4 acc[4][2] = {};

  stage(0, 0);
  asm volatile("s_waitcnt vmcnt(0)" ::: "memory");
  __syncthreads();

  for (int kt = 0; kt < 32; ++kt) {
    const int buf = kt & 1;
    if (kt < 31) stage(buf ^ 1, (kt + 1) * 32);

    short8 af[4], bfr[2];
    #pragma unroll
    for (int mi = 0; mi < 4; ++mi) {
      int row = wr * 64 + mi * 16 + lr;
      int sidx = (qg + (row >> 1)) & 3;
      af[mi] = *reinterpret_cast<const short8*>(&lds[buf][0][row * 32 + (sidx << 3)]);
    }
    #pragma unroll
    for (int ni = 0; ni < 2; ++ni) {
      int row = wc * 32 + ni * 16 + lr;
      int sidx = (qg + (row >> 1)) & 3;
      bfr[ni] = *reinterpret_cast<const short8*>(&lds[buf][1][row * 32 + (sidx << 3)]);
    }
    __builtin_amdgcn_s_setprio(1);
    #pragma unroll
    for (int mi = 0; mi < 4; ++mi)
      #pragma unroll
      for (int ni = 0; ni < 2; ++ni)
        acc[mi][ni] = MFMA(af[mi], bfr[ni], acc[mi][ni]);
    __builtin_amdgcn_s_setprio(0);

    if (kt < 31) {
      asm volatile("s_waitcnt vmcnt(0)" ::: "memory");
      __syncthreads();
    }
  }

  // epilogue: bias + layout-specific bf16 store
  #pragma unroll
  for (int ni = 0; ni < 2; ++ni) {
    int ng = n0 + wc * 32 + ni * 16 + lr;
    float bv_ = bias[ng];
    int h = ng >> 6, d = ng & 63;
    #pragma unroll
    for (int mi = 0; mi < 4; ++mi) {
      #pragma unroll
      for (int r = 0; r < 4; ++r) {
        int mg = m0 + wr * 64 + mi * 16 + qg * 4 + r;
        float val = acc[mi][ni][r] + bv_;
        int bb = mg >> 11, s = mg & (SEQ - 1);
        int bh = bb * HEADS + h;
        if (z == 0)
          oq[((size_t)bh * SEQ + s) * HDIM + d] = f2bf(val * QSCALE);
        else if (z == 1)
          ok[((size_t)bh * SEQ + s) * HDIM + d] = f2bf(val);
        else {
          size_t addr = (((size_t)bh * 2 + (d >> 5)) * (SEQ / 32) + (s >> 5)) * 1024
                      + (size_t)(d & 31) * 32 + (s & 31);
          ov[addr] = f2bf(val);
        }
      }
    }
  }
}

// ========== output-proj GEMM: 128x128, BK=64, 8 waves, 2-buf (round-13 best) ==========
__global__ __launch_bounds__(512, 4) void gemm_out128(
    const ushort* __restrict__ A0, const ushort* __restrict__ W0,
    const float* __restrict__ b0, float* __restrict__ of)
{
  __shared__ __align__(16) ushort lds[2][2][8192];   // [buf][A/W][128 x 64 bf16] = 64 KB

  const int nwg = 256;
  int lin = blockIdx.x + (blockIdx.y << 3);
  int swz = (lin & 7) * (nwg >> 3) + (lin >> 3);
  const int r_ = swz & 255;
  const int n0 = (r_ & 7) << 7;
  const int m0 = (r_ >> 3) << 7;

  const ushort* __restrict__ A = A0;
  const ushort* __restrict__ W = W0;
  const float*  __restrict__ bias = b0;

  const int t = threadIdx.x;
  const int lane = t & 63;
  const int wid = t >> 6;                    // 0..7
  const int wr = wid >> 2, wc = wid & 3;     // 2M x 4N waves; wave tile 64x32
  const int lr = lane & 15, qg = lane >> 4;

  auto stage = [&](int buf, int k0) {
    #pragma unroll
    for (int it = 0; it < 2; ++it) {
      int idx = it * 512 + t;
      int row = idx >> 3;
      int col = ((idx & 7) ^ (row & 7)) << 3;
      gl_lds16(&A[(size_t)(m0 + row) * EMBED + k0 + col], &lds[buf][0][idx * 8]);
    }
    #pragma unroll
    for (int it = 0; it < 2; ++it) {
      int idx = it * 512 + t;
      int row = idx >> 3;
      int col = ((idx & 7) ^ (row & 7)) << 3;
      gl_lds16(&W[(size_t)(n0 + row) * EMBED + k0 + col], &lds[buf][1][idx * 8]);
    }
  };

  f32x4 acc[4][2] = {};

  stage(0, 0);
  asm volatile("s_waitcnt vmcnt(0)" ::: "memory");
  __syncthreads();

  for (int kt = 0; kt < 16; ++kt) {
    const int buf = kt & 1;
    if (kt < 15) stage(buf ^ 1, (kt + 1) * 64);

    #pragma unroll
    for (int ks = 0; ks < 2; ++ks) {
      short8 af[4], bfr[2];
      #pragma unroll
      for (int mi = 0; mi < 4; ++mi) {
        int row = wr * 64 + mi * 16 + lr;
        int cp = (ks * 4 + qg) ^ (row & 7);
        af[mi] = *reinterpret_cast<const short8*>(&lds[buf][0][row * 64 + (cp << 3)]);
      }
      #pragma unroll
      for (int ni = 0; ni < 2; ++ni) {
        int row = wc * 32 + ni * 16 + lr;
        int cp = (ks * 4 + qg) ^ (row & 7);
        bfr[ni] = *reinterpret_cast<const short8*>(&lds[buf][1][row * 64 + (cp << 3)]);
      }
      __builtin_amdgcn_s_setprio(1);
      #pragma unroll
      for (int mi = 0; mi < 4; ++mi)
        #pragma unroll
        for (int ni = 0; ni < 2; ++ni)
          acc[mi][ni] = MFMA(af[mi], bfr[ni], acc[mi][ni]);
      __builtin_amdgcn_s_setprio(0);
    }

    if (kt < 15) {
      asm volatile("s_waitcnt vmcnt(0)" ::: "memory");
      __syncthreads();
    }
  }

  #pragma unroll
  for (int ni = 0; ni < 2; ++ni) {
    int ng = n0 + wc * 32 + ni * 16 + lr;
    float bv_ = bias[ng];
    #pragma unroll
    for (int mi = 0; mi < 4; ++mi) {
      #pragma unroll
      for (int r = 0; r < 4; ++r) {
        int mg = m0 + wr * 64 + mi * 16 + qg * 4 + r;
        of[(size_t)mg * EMBED + ng] = acc[mi][ni][r] + bv_;
      }
    }
  }
}

// ================= flash attention v7 (best measured: 57.6 us) =================
// LDS-staged shared K/V, 512 blocks x 4 waves, conflict-free K (pi-XOR) and V
// (row>>1 XOR) swizzles, no-max softmax, fused pairwise exp2+mask+cvtpk.
__global__ __launch_bounds__(256, 2) void attn(
    const ushort* __restrict__ qws, const ushort* __restrict__ kws,
    const ushort* __restrict__ vws, const unsigned* __restrict__ mbits,
    ushort* __restrict__ xws)
{
  const int t = threadIdx.x;
  const int wid = t >> 6;
  const int l = t & 63;
  const int q31 = l & 31;
  const int h = l >> 5;

  const int L = blockIdx.x;
  const int j = L >> 3;
  const int bh = ((L & 7) << 2) + (j >> 4);   // XCD x owns bh {4x..4x+3}
  const int q0 = (j & 15) << 7;               // 128-row q block
  const int b = bh >> 4, head = bh & 15;

  __shared__ __align__(16) ushort lds[9216];   // 18 KB

  const int qrow = q0 + wid * 32 + q31;
  const ushort* qp = qws + ((size_t)bh * SEQ + qrow) * HDIM + 8 * h;
  short8 qf[4];
  #pragma unroll
  for (int s = 0; s < 4; ++s)
    qf[s] = *reinterpret_cast<const short8*>(qp + 16 * s);

  const int rp = (q31 & 19) | ((q31 & 4) << 1) | ((q31 & 8) >> 1);  // pi(q31)

  int koff[4];
  #pragma unroll
  for (int i = 0; i < 4; ++i)
    koff[i] = rp * 64 + (((h + 2 * i) ^ (rp & 7)) << 3);
  int voff[2][2];
  #pragma unroll
  for (int sb = 0; sb < 2; ++sb)
    #pragma unroll
    for (int jj = 0; jj < 2; ++jj)
      voff[sb][jj] = sb * 1024 + q31 * 32 + (((h + 2 * jj) ^ ((q31 >> 1) & 3)) << 3);

  const ushort* ksb = kws + (size_t)bh * SEQ * HDIM
                    + ((t >> 3) << 6) + (((t & 7) ^ ((t >> 3) & 7)) << 3);
  const int vsub = t >> 7, vd = (t >> 2) & 31, vc = t & 3;
  const ushort* vsb = vws + (((size_t)bh * 2 + vsub) << 16)
                    + vd * 32 + ((vc ^ ((vd >> 1) & 3)) << 3);
  ushort* kd0 = lds + t * 8;
  ushort* vd0 = lds + 2048 + t * 8;

  const unsigned* mp = mbits + (size_t)(b * SEQ + qrow) * (SEQ / 32);

  f32x16 accT[2] = {};
  float ls0 = 0.f, ls1 = 0.f, ls2 = 0.f, ls3 = 0.f;

  auto STAGE = [&](int tile, int bb) {
    gl_lds16(ksb + (size_t)tile * 2048, kd0 + bb);
    gl_lds16(vsb + (size_t)tile * 1024, vd0 + bb);
  };

  auto COMP = [&](int bb, unsigned mwc) {
    const ushort* kb = lds + bb;
    const ushort* vb = lds + bb + 2048;
    short8 kf0 = *reinterpret_cast<const short8*>(kb + koff[0]);
    short8 kf1 = *reinterpret_cast<const short8*>(kb + koff[1]);
    short8 kf2 = *reinterpret_cast<const short8*>(kb + koff[2]);
    short8 kf3 = *reinterpret_cast<const short8*>(kb + koff[3]);
    __builtin_amdgcn_s_setprio(1);
    f32x16 s = {};
    s = MFMA32(kf0, qf[0], s);
    s = MFMA32(kf1, qf[1], s);
    s = MFMA32(kf2, qf[2], s);
    s = MFMA32(kf3, qf[3], s);
    __builtin_amdgcn_s_setprio(0);

    short8 vf0 = *reinterpret_cast<const short8*>(vb + voff[0][0]);
    short8 vf1 = *reinterpret_cast<const short8*>(vb + voff[0][1]);
    short8 vf2 = *reinterpret_cast<const short8*>(vb + voff[1][0]);
    short8 vf3 = *reinterpret_cast<const short8*>(vb + voff[1][1]);

    unsigned msh = mwc >> (8 * h);
    union U { unsigned u[4]; short8 s8; } p0u, p1u;
    #pragma unroll
    for (int i = 0; i < 8; ++i) {
      const int r0 = 2 * i, r1 = 2 * i + 1;
      float e0 = ((msh >> ((r0 & 7) + 16 * (r0 >> 3))) & 1u) ? __builtin_amdgcn_exp2f(s[r0]) : 0.0f;
      float e1 = ((msh >> ((r1 & 7) + 16 * (r1 >> 3))) & 1u) ? __builtin_amdgcn_exp2f(s[r1]) : 0.0f;
      if ((i & 3) == 0) ls0 += e0 + e1;
      else if ((i & 3) == 1) ls1 += e0 + e1;
      else if ((i & 3) == 2) ls2 += e0 + e1;
      else ls3 += e0 + e1;
      if (i < 4) p0u.u[i] = cvtpk(e0, e1);
      else       p1u.u[i - 4] = cvtpk(e0, e1);
    }

    __builtin_amdgcn_s_setprio(1);
    accT[0] = MFMA32(vf0, p0u.s8, accT[0]);
    accT[0] = MFMA32(vf1, p1u.s8, accT[0]);
    accT[1] = MFMA32(vf2, p0u.s8, accT[1]);
    accT[1] = MFMA32(vf3, p1u.s8, accT[1]);
    __builtin_amdgcn_s_setprio(0);
  };

  unsigned mw = *mp; ++mp;
  STAGE(0, 0);
  asm volatile("s_waitcnt vmcnt(0)" ::: "memory");
  __syncthreads();

  #pragma unroll 1
  for (int it = 0; it < 32; ++it) {
    STAGE(2 * it + 1, 4096);
    unsigned mn = *mp; ++mp;
    COMP(0, mw);
    asm volatile("s_waitcnt vmcnt(0)" ::: "memory");
    __syncthreads();
    mw = mn;
    if (it < 31) STAGE(2 * it + 2, 0);
    mn = *mp; ++mp;
    COMP(4096, mw);
    asm volatile("s_waitcnt vmcnt(0)" ::: "memory");
    __syncthreads();
    mw = mn;
  }

  float lsum = (ls0 + ls1) + (ls2 + ls3);
  float lrow = lsum + __shfl_xor(lsum, 32);
  float inv = 1.0f / lrow;

  ushort* xb = lds + wid * 2304;   // [32][72] per wave
  #pragma unroll
  for (int nb = 0; nb < 2; ++nb)
    #pragma unroll
    for (int rg = 0; rg < 4; ++rg) {
      int dbase = 32 * nb + 8 * rg + 4 * h;
      uint2 pk = make_uint2(
          packbf(accT[nb][4 * rg] * inv,     accT[nb][4 * rg + 1] * inv),
          packbf(accT[nb][4 * rg + 2] * inv, accT[nb][4 * rg + 3] * inv));
      *reinterpret_cast<uint2*>(&xb[q31 * 72 + dbase]) = pk;
    }
  asm volatile("" ::: "memory");   // same-wave LDS order
  #pragma unroll
  for (int pp = 0; pp < 4; ++pp) {
    int row = pp * 8 + (l >> 3);
    int col = (l & 7) * 8;
    short8 xv = *reinterpret_cast<const short8*>(&xb[row * 72 + col]);
    *reinterpret_cast<short8*>(
        &xws[((size_t)b * SEQ + q0 + wid * 32 + row) * EMBED + head * HDIM + col]) = xv;
  }
}

// ================= launch =================
extern "C" void kernel_launch(void* const* d_in, const int* in_sizes, int n_in,
                              void* d_out, int out_size, void* d_ws, size_t ws_size,
                              hipStream_t stream) {
  (void)in_sizes; (void)n_in; (void)out_size; (void)ws_size;
  const float* query = (const float*)d_in[0];
  const float* key   = (const float*)d_in[1];
  const float* value = (const float*)d_in[2];
  const int*   mask  = (const int*)d_in[3];
  const float* Wq = (const float*)d_in[4];  const float* bq = (const float*)d_in[5];
  const float* Wk = (const float*)d_in[6];  const float* bk = (const float*)d_in[7];
  const float* Wv = (const float*)d_in[8];  const float* bv = (const float*)d_in[9];
  const float* Wo = (const float*)d_in[10]; const float* bo = (const float*)d_in[11];
  float* out = (float*)d_out;

  const size_t NQKV = (size_t)BATCH * HEADS * SEQ * HDIM;   // 4,194,304
  const size_t NW   = (size_t)EMBED * EMBED;                // 1,048,576
  ushort* qws = (ushort*)d_ws;
  ushort* kws = qws + NQKV;
  ushort* vws = kws + NQKV;
  ushort* xws = vws + NQKV;
  unsigned* mbits = (unsigned*)(xws + NQKV);                // 1 MB packed mask
  ushort* aqb = (ushort*)(mbits + (size_t)BATCH * SEQ * SEQ / 32);
  ushort* akb = aqb + NQKV;
  ushort* avb = akb + NQKV;
  ushort* wqb = avb + NQKV;
  ushort* wkb = wqb + NW;
  ushort* wvb = wkb + NW;
  ushort* wob = wvb + NW;

  // z=0..6: bf16 converts (inputs + 4 weights); z=7: mask bit-pack (16 elems/thread)
  prep<<<dim3(2048, 1, 8), 256, 0, stream>>>(
      query, key, value, Wq, Wk, Wv, Wo, mask,
      aqb, akb, avb, wqb, wkb, wvb, wob, (ushort*)mbits);

  gemm_qkv32<<<dim3(8, 96), 512, 0, stream>>>(
      aqb, akb, avb, wqb, wkb, wvb, bq, bk, bv, qws, kws, vws);

  attn<<<dim3(512), 256, 0, stream>>>(qws, kws, vws, mbits, xws);

  gemm_out128<<<dim3(8, 32), 512, 0, stream>>>(xws, wob, bo, out);
}